// Round 7
// baseline (170.103 us; speedup 1.0000x reference)
//
#include <hip/hip_runtime.h>
#include <cstdint>

// out[b] = x[b] @ C[b],  C[b] = sum_h Wq[h] M[b,h] Wo[h],  M = Wk^T (x^T x) Wv
// R17: TWO dispatches.  Budget model: dur = 45 (harness fill) + 14.5/launch
// + work.  3 launches put the floor at ~124; 2 launches + ~33us work -> ~110.
//   k_fused: prep (agent-scope write-through stores) -> epoch barrier
//            (fence-free; device-global monotonic counters, replay-safe:
//            R16's 20ms profiled k_main was the non-replay-safe counter) ->
//            xtx (bf16 G chunk-partials, symmetric => transposed packing
//            free; NO atomics, NO zero-init) || Q' -> xtx-only epoch gate,
//            last 128 finishers run mid (T2=Wk^T G, Mp bf16 partials).
//   k_out:   R16's (passed) Q'.(M.Wo) 128x128 tiles.
// Coherence: within-kernel crossings = sc1 write-through stores + first-
// touch reads (kernel-start inv clears stale L2); cross-launch = HW wb/inv.

#define BDIM 2
#define LDIM 4096
#define DIN 512
#define HDIM 8
#define DK 64
#define DV 64
#define DOUT 512
#define NBLKF 512
#define NXTX 256
#define NMID 128
#define NCH 4

using bf16_t = __bf16;
typedef __bf16 bf16x8 __attribute__((ext_vector_type(8)));
typedef float floatx4 __attribute__((ext_vector_type(4)));

constexpr size_t OFF_XB  = 0;
constexpr size_t OFF_XT  = OFF_XB  + (size_t)BDIM * LDIM * DIN * 2;
constexpr size_t OFF_WQT = OFF_XT  + (size_t)BDIM * LDIM * DIN * 2;
constexpr size_t OFF_WKT = OFF_WQT + (size_t)HDIM * DK * DIN * 2;
constexpr size_t OFF_WVT = OFF_WKT + (size_t)HDIM * DK * DIN * 2;
constexpr size_t OFF_WOT = OFF_WVT + (size_t)HDIM * DV * DIN * 2;
constexpr size_t OFF_QP  = OFF_WOT + (size_t)HDIM * DOUT * DV * 2;
constexpr size_t OFF_GP  = OFF_QP  + (size_t)BDIM * LDIM * DIN * 2;
constexpr size_t OFF_MP  = OFF_GP  + (size_t)NCH * BDIM * DIN * DIN * 2;

// Monotonic epoch counters: zero-initialized at module load, NEVER reset.
// Each k_fused launch consumes exactly NBLKF / NXTX increments -> epoch
// alignment is invariant across iterations AND rocprof replays.
__device__ unsigned g_ctr[2];

__device__ __forceinline__ unsigned short f2bf(float f) {
    unsigned int u = __builtin_bit_cast(unsigned int, f);
    u += 0x7FFFu + ((u >> 16) & 1u);
    return (unsigned short)(u >> 16);
}

__device__ __forceinline__ float bf2f(unsigned short u) {
    unsigned int v = ((unsigned int)u) << 16;
    return __builtin_bit_cast(float, v);
}

__device__ __forceinline__ void gld_lds16(const void* g, void* l) {
    __builtin_amdgcn_global_load_lds(
        (const __attribute__((address_space(1))) void*)g,
        (__attribute__((address_space(3))) void*)l, 16, 0, 0);
}

// agent-scope relaxed stores: sc1 write-through to IF$ (coherent point).
__device__ __forceinline__ void st_agent64(unsigned short* p, ushort4 u) {
    unsigned long long v = (unsigned long long)u.x |
                           ((unsigned long long)u.y << 16) |
                           ((unsigned long long)u.z << 32) |
                           ((unsigned long long)u.w << 48);
    __hip_atomic_store((unsigned long long*)p, v, __ATOMIC_RELAXED,
                       __HIP_MEMORY_SCOPE_AGENT);
}
__device__ __forceinline__ void st_agent32(unsigned short* p, unsigned v) {
    __hip_atomic_store((unsigned*)p, v, __ATOMIC_RELAXED,
                       __HIP_MEMORY_SCOPE_AGENT);
}

// ---------------- TN MFMA GEMM tile (bf16 plain-store epilogue) -----------
template <int BM, int BN, int BK>
__device__ __forceinline__ void gemm_tn(char* smem, const bf16_t* A,
                                        const bf16_t* B, unsigned short* Cp,
                                        int K, int lda, int ldb, int ldc,
                                        int tm, int tn) {
    constexpr int WM = BM / 2, WN = BN / 2;
    constexpr int FM = WM / 16, FN = WN / 16;
    constexpr int CPR = BK / 8;
    bf16_t* As = (bf16_t*)smem;
    bf16_t* Bs = As + BM * BK;
    const int tid = threadIdx.x;
    const int lane = tid & 63;
    const int wr = (tid >> 7) & 1;
    const int wc = (tid >> 6) & 1;

    A += (size_t)tm * lda;
    B += (size_t)tn * ldb;

    floatx4 acc[FM][FN] = {};

    for (int k0 = 0; k0 < K; k0 += BK) {
#pragma unroll
        for (int i = 0; i < (BM * CPR) / 256; ++i) {
            int c = i * 256 + tid;
            int m = c / CPR, kc = c % CPR;
            gld_lds16(A + (size_t)m * lda + k0 + kc * 8, As + c * 8);
        }
#pragma unroll
        for (int i = 0; i < (BN * CPR) / 256; ++i) {
            int c = i * 256 + tid;
            int m = c / CPR, kc = c % CPR;
            gld_lds16(B + (size_t)m * ldb + k0 + kc * 8, Bs + c * 8);
        }
        __syncthreads();

#pragma unroll
        for (int kk = 0; kk < BK; kk += 32) {
            bf16x8 aF[FM], bF[FN];
#pragma unroll
            for (int fm = 0; fm < FM; ++fm)
                aF[fm] = *(const bf16x8*)(As + (wr * WM + fm * 16 + (lane & 15)) * BK +
                                          kk + (lane >> 4) * 8);
#pragma unroll
            for (int fn = 0; fn < FN; ++fn)
                bF[fn] = *(const bf16x8*)(Bs + (wc * WN + fn * 16 + (lane & 15)) * BK +
                                          kk + (lane >> 4) * 8);
#pragma unroll
            for (int fm = 0; fm < FM; ++fm)
#pragma unroll
                for (int fn = 0; fn < FN; ++fn)
                    acc[fm][fn] = __builtin_amdgcn_mfma_f32_16x16x32_bf16(
                        aF[fm], bF[fn], acc[fm][fn], 0, 0, 0);
        }
        __syncthreads();
    }

    const int cr4 = (lane >> 4) * 4;
    const int cn = lane & 15;
#pragma unroll
    for (int fm = 0; fm < FM; ++fm)
#pragma unroll
        for (int fn = 0; fn < FN; ++fn)
#pragma unroll
            for (int r = 0; r < 4; ++r) {
                int m = tm + wr * WM + fm * 16 + cr4 + r;
                int n = tn + wc * WN + fn * 16 + cn;
                Cp[(size_t)m * ldc + n] = f2bf(acc[fm][fn][r]);
            }
}

// ---------------- xtx job: bf16 G chunk-partial, agent stores -------------
// Gp[ch,b][n][m] = tile value (m,n); each chunk partial is SYMMETRIC so the
// transposed packing (m-pairs in-lane) stores the same matrix row-major.
__device__ void xtx_job(int bid, char* smem, const bf16_t* xT,
                        unsigned short* GpB) {
    const int tid = threadIdx.x, lane = tid & 63;
    const int wr = (tid >> 7) & 1, wc = (tid >> 6) & 1;
    const int cr4 = (lane >> 4) * 4, cn = lane & 15;
    const int b = bid >> 7, r = bid & 127;
    const int ch = r >> 5, t = r & 31;
    const int i0 = (t >> 3) * 128, j0 = (t & 7) * 64;
    bf16_t* As = (bf16_t*)smem;   // 128x64
    bf16_t* Bs = As + 128 * 64;   // 64x64
    const bf16_t* Ag = xT + (size_t)b * DIN * LDIM + ch * 1024 +
                       (size_t)i0 * LDIM;
    const bf16_t* Bg = xT + (size_t)b * DIN * LDIM + ch * 1024 +
                       (size_t)j0 * LDIM;

    floatx4 acc[4][2] = {};
    for (int k0 = 0; k0 < 1024; k0 += 64) {
#pragma unroll
        for (int i = 0; i < 4; ++i) {
            int c = i * 256 + tid, m = c >> 3, kc = c & 7;
            gld_lds16(Ag + (size_t)m * LDIM + k0 + kc * 8, As + c * 8);
        }
#pragma unroll
        for (int i = 0; i < 2; ++i) {
            int c = i * 256 + tid, m = c >> 3, kc = c & 7;
            gld_lds16(Bg + (size_t)m * LDIM + k0 + kc * 8, Bs + c * 8);
        }
        __syncthreads();
#pragma unroll
        for (int kk = 0; kk < 64; kk += 32) {
            bf16x8 aF[4], bF[2];
#pragma unroll
            for (int fm = 0; fm < 4; ++fm)
                aF[fm] = *(const bf16x8*)(As + (wr * 64 + fm * 16 + cn) * 64 +
                                          kk + (lane >> 4) * 8);
#pragma unroll
            for (int fn = 0; fn < 2; ++fn)
                bF[fn] = *(const bf16x8*)(Bs + (wc * 32 + fn * 16 + cn) * 64 +
                                          kk + (lane >> 4) * 8);
#pragma unroll
            for (int fm = 0; fm < 4; ++fm)
#pragma unroll
                for (int fn = 0; fn < 2; ++fn)
                    acc[fm][fn] = __builtin_amdgcn_mfma_f32_16x16x32_bf16(
                        aF[fm], bF[fn], acc[fm][fn], 0, 0, 0);
        }
        __syncthreads();
    }

    unsigned short* Gt = GpB + (size_t)(ch * 2 + b) * DIN * DIN;
#pragma unroll
    for (int fm = 0; fm < 4; ++fm)
#pragma unroll
        for (int fn = 0; fn < 2; ++fn) {
            int m = i0 + wr * 64 + fm * 16 + cr4;
            int n = j0 + wc * 32 + fn * 16 + cn;
            unsigned a01 = (unsigned)f2bf(acc[fm][fn][0]) |
                           ((unsigned)f2bf(acc[fm][fn][1]) << 16);
            unsigned a23 = (unsigned)f2bf(acc[fm][fn][2]) |
                           ((unsigned)f2bf(acc[fm][fn][3]) << 16);
            st_agent32(Gt + (size_t)n * DIN + m, a01);
            st_agent32(Gt + (size_t)n * DIN + m + 2, a23);
        }
}

// ---------------- mid job: T2 = Wk^T G (sum 4 partials), Mp bf16 ----------
__device__ void mid_job(int id, char* smem, const bf16_t* WkT,
                        const bf16_t* WvT, const unsigned short* GpB,
                        unsigned short* Mp) {
    const int tid = threadIdx.x, lane = tid & 63;
    const int wr = (tid >> 7) & 1, wc = (tid >> 6) & 1;
    const int cr4 = (lane >> 4) * 4, cn = lane & 15;
    const int h = id & 7, b = (id >> 3) & 1, jt = id >> 4;  // jt 0..7
    const int j0 = jt * 64;
    bf16_t* As  = (bf16_t*)smem;                 // 64x64
    bf16_t* Bs  = (bf16_t*)(smem + 8192);        // 64x64
    bf16_t* T2s = (bf16_t*)(smem + 16384);       // [64][72]
    bf16_t* Vs  = (bf16_t*)(smem + 25600);       // 64x64
    const bf16_t* Ah = WkT + (size_t)h * DK * DIN;
    const bf16_t* Vh = WvT + (size_t)h * DV * DIN;

    floatx4 accT[2][2] = {};
    for (int k0 = 0; k0 < DIN; k0 += 64) {
#pragma unroll
        for (int i = 0; i < 2; ++i) {
            int c = i * 256 + tid, m = c >> 3, kc = c & 7;
            gld_lds16(Ah + (size_t)m * DIN + k0 + kc * 8, As + c * 8);
        }
#pragma unroll
        for (int i = 0; i < 2; ++i) {
            int c = i * 256 + tid, n = c >> 3, kc = c & 7;
            const unsigned short* g = GpB + (size_t)b * DIN * DIN +
                                      (size_t)(j0 + n) * DIN + k0 + kc * 8;
            float s[8] = {0.f, 0.f, 0.f, 0.f, 0.f, 0.f, 0.f, 0.f};
#pragma unroll
            for (int ch = 0; ch < NCH; ++ch) {
                uint4 u = *(const uint4*)(g + (size_t)ch * 2 * DIN * DIN);
                const unsigned short* e = (const unsigned short*)&u;
#pragma unroll
                for (int q = 0; q < 8; ++q) s[q] += bf2f(e[q]);
            }
            unsigned short o[8];
#pragma unroll
            for (int q = 0; q < 8; ++q) o[q] = f2bf(s[q]);
            *(uint4*)((unsigned short*)Bs + (size_t)c * 8) = *(const uint4*)o;
        }
        __syncthreads();
#pragma unroll
        for (int kk = 0; kk < 64; kk += 32) {
            bf16x8 aF[2], bF[2];
#pragma unroll
            for (int f = 0; f < 2; ++f) {
                aF[f] = *(const bf16x8*)(As + (wr * 32 + f * 16 + cn) * 64 + kk +
                                         (lane >> 4) * 8);
                bF[f] = *(const bf16x8*)(Bs + (wc * 32 + f * 16 + cn) * 64 + kk +
                                         (lane >> 4) * 8);
            }
#pragma unroll
            for (int fm = 0; fm < 2; ++fm)
#pragma unroll
                for (int fn = 0; fn < 2; ++fn)
                    accT[fm][fn] = __builtin_amdgcn_mfma_f32_16x16x32_bf16(
                        aF[fm], bF[fn], accT[fm][fn], 0, 0, 0);
        }
        __syncthreads();
    }
    // accT -> T2s [dk][j] (pad 72), stage Wv j-slice
#pragma unroll
    for (int fm = 0; fm < 2; ++fm)
#pragma unroll
        for (int fn = 0; fn < 2; ++fn)
#pragma unroll
            for (int r = 0; r < 4; ++r)
                ((unsigned short*)T2s)[(wr * 32 + fm * 16 + cr4 + r) * 72 +
                                       wc * 32 + fn * 16 + cn] =
                    f2bf(accT[fm][fn][r]);
#pragma unroll
    for (int i = 0; i < 2; ++i) {
        int c = i * 256 + tid, v = c >> 3, kc = c & 7;
        gld_lds16(Vh + (size_t)v * DIN + j0 + kc * 8, Vs + c * 8);
    }
    __syncthreads();

    floatx4 accM[2][2] = {};
#pragma unroll
    for (int kk = 0; kk < 64; kk += 32) {
        bf16x8 aF[2], bF[2];
#pragma unroll
        for (int f = 0; f < 2; ++f) {
            aF[f] = *(const bf16x8*)(T2s + (wr * 32 + f * 16 + cn) * 72 + kk +
                                     (lane >> 4) * 8);
            bF[f] = *(const bf16x8*)(Vs + (wc * 32 + f * 16 + cn) * 64 + kk +
                                     (lane >> 4) * 8);
        }
#pragma unroll
        for (int fm = 0; fm < 2; ++fm)
#pragma unroll
            for (int fn = 0; fn < 2; ++fn)
                accM[fm][fn] = __builtin_amdgcn_mfma_f32_16x16x32_bf16(
                    aF[fm], bF[fn], accM[fm][fn], 0, 0, 0);
    }
    unsigned short* MpD = Mp + ((size_t)((jt * BDIM + b) * HDIM + h)) * (DK * DV);
#pragma unroll
    for (int fm = 0; fm < 2; ++fm)
#pragma unroll
        for (int fn = 0; fn < 2; ++fn)
#pragma unroll
            for (int r = 0; r < 4; ++r)
                MpD[(wr * 32 + fm * 16 + cr4 + r) * 64 + wc * 32 + fn * 16 + cn] =
                    f2bf(accM[fm][fn][r]);
}

// ---------------- K1: fused prep | barrier | xtx+Q' | gate | mid ----------
__global__ __launch_bounds__(256) void k_fused(
    const float* __restrict__ x, const float* __restrict__ Wq,
    const float* __restrict__ Wk, const float* __restrict__ Wv,
    const float* __restrict__ Wo, char* __restrict__ ws) {
    __shared__ __align__(16) char smem[34816];
    __shared__ unsigned s_rank;
    unsigned short* xb  = (unsigned short*)(ws + OFF_XB);
    unsigned short* xT  = (unsigned short*)(ws + OFF_XT);
    unsigned short* WqT = (unsigned short*)(ws + OFF_WQT);
    unsigned short* WkT = (unsigned short*)(ws + OFF_WKT);
    unsigned short* WvT = (unsigned short*)(ws + OFF_WVT);
    unsigned short* WoT = (unsigned short*)(ws + OFF_WOT);
    unsigned short* Qp  = (unsigned short*)(ws + OFF_QP);
    unsigned short* GpB = (unsigned short*)(ws + OFF_GP);
    unsigned short* Mp  = (unsigned short*)(ws + OFF_MP);

    const int bid = blockIdx.x;
    const int tid = threadIdx.x;

    // ---------------- phase A: prep (1280 jobs, grid-stride) ---------------
    {
        unsigned short (*T)[65] = (unsigned short (*)[65])smem;
        const int tr = tid >> 4, tc4 = (tid & 15) * 4;
        for (int j = bid; j < 1280; j += NBLKF) {
            if (j < 1024) {  // x 64x64 tile -> xb (row) + xT (transposed)
                const int b = j >> 9, q = j & 511, lt = q >> 3, it = q & 7;
                const float* src = x + (size_t)b * LDIM * DIN +
                                   (size_t)lt * 64 * DIN + it * 64;
                unsigned short* d0 = xb + (size_t)b * LDIM * DIN +
                                     (size_t)lt * 64 * DIN + it * 64;
                unsigned short* d1 = xT + (size_t)b * DIN * LDIM +
                                     (size_t)it * 64 * LDIM + lt * 64;
#pragma unroll
                for (int p = 0; p < 4; ++p) {
                    int r = p * 16 + tr;
                    float4 v = *(const float4*)(src + (size_t)r * DIN + tc4);
                    ushort4 u = make_ushort4(f2bf(v.x), f2bf(v.y), f2bf(v.z),
                                             f2bf(v.w));
                    st_agent64(d0 + (size_t)r * DIN + tc4, u);
                    T[r][tc4 + 0] = u.x; T[r][tc4 + 1] = u.y;
                    T[r][tc4 + 2] = u.z; T[r][tc4 + 3] = u.w;
                }
                __syncthreads();
#pragma unroll
                for (int p = 0; p < 4; ++p) {
                    int c = p * 16 + tr;
                    ushort4 u = make_ushort4(T[tc4 + 0][c], T[tc4 + 1][c],
                                             T[tc4 + 2][c], T[tc4 + 3][c]);
                    st_agent64(d1 + (size_t)c * LDIM + tc4, u);
                }
                __syncthreads();
            } else {
                const int q = j - 1024;
                const int t = q & 7, h = (q >> 3) & 7, typ = q >> 6;
                const float* src;
                unsigned short* dst;
                int rows, cols, r0, c0;
                if (typ == 0) { src = Wq + (size_t)h * DIN * DK;
                                dst = WqT + (size_t)h * DK * DIN;
                                rows = DIN; cols = DK; r0 = t * 64; c0 = 0; }
                else if (typ == 1) { src = Wk + (size_t)h * DIN * DK;
                                dst = WkT + (size_t)h * DK * DIN;
                                rows = DIN; cols = DK; r0 = t * 64; c0 = 0; }
                else if (typ == 2) { src = Wv + (size_t)h * DIN * DV;
                                dst = WvT + (size_t)h * DV * DIN;
                                rows = DIN; cols = DV; r0 = t * 64; c0 = 0; }
                else { src = Wo + (size_t)h * DV * DOUT;
                                dst = WoT + (size_t)h * DOUT * DV;
                                rows = DV; cols = DOUT; r0 = 0; c0 = t * 64; }
#pragma unroll
                for (int p = 0; p < 4; ++p) {
                    int r = p * 16 + tr;
                    float4 v = *(const float4*)(src + (size_t)(r0 + r) * cols +
                                                c0 + tc4);
                    T[r][tc4 + 0] = f2bf(v.x); T[r][tc4 + 1] = f2bf(v.y);
                    T[r][tc4 + 2] = f2bf(v.z); T[r][tc4 + 3] = f2bf(v.w);
                }
                __syncthreads();
#pragma unroll
                for (int p = 0; p < 4; ++p) {
                    int c = p * 16 + tr;
                    ushort4 u = make_ushort4(T[tc4 + 0][c], T[tc4 + 1][c],
                                             T[tc4 + 2][c], T[tc4 + 3][c]);
                    st_agent64(dst + (size_t)(c0 + c) * rows + r0 + tc4, u);
                }
                __syncthreads();
            }
        }
    }

    // ---------------- epoch barrier, all 512 blocks (fence-free) -----------
    __syncthreads();  // drains vmcnt(0): agent stores are through to IF$
    if (tid == 0) {
        unsigned old = __hip_atomic_fetch_add(&g_ctr[0], 1u, __ATOMIC_RELAXED,
                                              __HIP_MEMORY_SCOPE_AGENT);
        unsigned tgt = (old | (NBLKF - 1)) + 1;  // next multiple of NBLKF
        while ((int)(__hip_atomic_load(&g_ctr[0], __ATOMIC_RELAXED,
                                       __HIP_MEMORY_SCOPE_AGENT) - tgt) < 0)
            __builtin_amdgcn_s_sleep(16);
    }
    __syncthreads();

    // ---------------- phase B --------------------------------------------
    if (bid < NXTX) {
        xtx_job(bid, smem, (const bf16_t*)xT, GpB);
        // xtx-only epoch gate; last NMID finishers run mid jobs
        __syncthreads();
        if (tid == 0) {
            unsigned old = __hip_atomic_fetch_add(&g_ctr[1], 1u,
                                                  __ATOMIC_RELAXED,
                                                  __HIP_MEMORY_SCOPE_AGENT);
            s_rank = old & (NXTX - 1);
            if (s_rank >= NXTX - NMID) {
                unsigned tgt = (old | (NXTX - 1)) + 1;
                while ((int)(__hip_atomic_load(&g_ctr[1], __ATOMIC_RELAXED,
                                               __HIP_MEMORY_SCOPE_AGENT) -
                             tgt) < 0)
                    __builtin_amdgcn_s_sleep(8);
            }
        }
        __syncthreads();
        if (s_rank >= NXTX - NMID)
            mid_job((int)s_rank - (NXTX - NMID), smem, (const bf16_t*)WkT,
                    (const bf16_t*)WvT, GpB, Mp);
    } else {
        // Q'[b][l][(h,dk)] = sum_i xb[l][i] * WqT[(h,dk)][i]  (128x128 tile)
        const int q = bid - NXTX;
        const int b = q >> 7, t = q & 127;
        const int lt = t >> 2, nt = t & 3;
        gemm_tn<128, 128, 64>(smem, (const bf16_t*)xb + (size_t)b * LDIM * DIN,
                              (const bf16_t*)WqT,
                              Qp + (size_t)b * LDIM * (HDIM * DK), DIN, DIN,
                              DIN, HDIM * DK, lt * 128, nt * 128);
    }
}

// ---------------- K2: out' (R16's, unchanged) -----------------------------
__global__ __launch_bounds__(256) void k_out(const char* __restrict__ ws,
                                             float* __restrict__ out) {
    __shared__ __align__(16) bf16_t Qs[128 * 64];
    __shared__ __align__(16) bf16_t Ws[128 * 64];
    __shared__ __align__(16) bf16_t Ms[64 * 72];
    __shared__ __align__(16) bf16_t PTs[128 * 72];
    const bf16_t* WoT = (const bf16_t*)(ws + OFF_WOT);
    const bf16_t* Qp  = (const bf16_t*)(ws + OFF_QP);
    const unsigned short* Mp = (const unsigned short*)(ws + OFF_MP);

    const int lt = blockIdx.x, nt = blockIdx.y, b = blockIdx.z;
    const int l0 = lt * 128, o0 = nt * 128;
    const int tid = threadIdx.x, lane = tid & 63;
    const int wr = (tid >> 7) & 1, wc = (tid >> 6) & 1;
    const int cr4 = (lane >> 4) * 4, cn = lane & 15;

    floatx4 acc[4][4] = {};

    for (int h = 0; h < HDIM; ++h) {
        // stage Ms: sum 8 bf16 jt-partials -> bf16 [dk][v] (pad 72)
        {
            const int dk = tid >> 2, v0 = (tid & 3) * 16;
            float s[16] = {0.f, 0.f, 0.f, 0.f, 0.f, 0.f, 0.f, 0.f,
                           0.f, 0.f, 0.f, 0.f, 0.f, 0.f, 0.f, 0.f};
#pragma unroll
            for (int p = 0; p < 8; ++p) {
                const unsigned short* mp =
                    Mp + ((size_t)((p * BDIM + b) * HDIM + h)) * (DK * DV) +
                    dk * 64 + v0;
                uint4 u0 = *(const uint4*)mp;
                uint4 u1 = *(const uint4*)(mp + 8);
                const unsigned short* e0 = (const unsigned short*)&u0;
                const unsigned short* e1 = (const unsigned short*)&u1;
#pragma unroll
                for (int q = 0; q < 8; ++q) {
                    s[q] += bf2f(e0[q]);
                    s[8 + q] += bf2f(e1[q]);
                }
            }
            unsigned short o[16];
#pragma unroll
            for (int q = 0; q < 16; ++q) o[q] = f2bf(s[q]);
            unsigned short* d = (unsigned short*)Ms + dk * 72 + v0;
            *(uint4*)d = *(const uint4*)o;
            *(uint4*)(d + 8) = *(const uint4*)(o + 8);
        }
#pragma unroll
        for (int i = 0; i < 4; ++i) {
            int c = i * 256 + tid, m = c >> 3, kc = c & 7;
            gld_lds16(WoT + ((size_t)h * DOUT + o0 + m) * DV + kc * 8,
                      Ws + c * 8);
            gld_lds16(Qp + (size_t)b * LDIM * 512 + (size_t)(l0 + m) * 512 +
                          h * 64 + kc * 8,
                      Qs + c * 8);
        }
        __syncthreads();

        floatx4 accP[2][4] = {};
#pragma unroll
        for (int kk = 0; kk < 64; kk += 32) {
            bf16x8 aF[2], bF[4];
#pragma unroll
            for (int f = 0; f < 2; ++f)
                aF[f] = *(const bf16x8*)(Ms + (wr * 32 + f * 16 + cn) * 72 + kk +
                                         (lane >> 4) * 8);
#pragma unroll
            for (int f = 0; f < 4; ++f)
                bF[f] = *(const bf16x8*)(Ws + (wc * 64 + f * 16 + cn) * 64 + kk +
                                         (lane >> 4) * 8);
#pragma unroll
            for (int fm = 0; fm < 2; ++fm)
#pragma unroll
                for (int fn = 0; fn < 4; ++fn)
                    accP[fm][fn] = __builtin_amdgcn_mfma_f32_16x16x32_bf16(
                        aF[fm], bF[fn], accP[fm][fn], 0, 0, 0);
        }
#pragma unroll
        for (int fm = 0; fm < 2; ++fm)
#pragma unroll
            for (int fn = 0; fn < 4; ++fn)
#pragma unroll
                for (int r = 0; r < 4; ++r)
                    ((unsigned short*)PTs)[(wc * 64 + fn * 16 + cn) * 72 +
                                           wr * 32 + fm * 16 + cr4 + r] =
                        f2bf(accP[fm][fn][r]);
        __syncthreads();

#pragma unroll
        for (int kk = 0; kk < 64; kk += 32) {
            bf16x8 aF[4], bF[4];
#pragma unroll
            for (int f = 0; f < 4; ++f) {
                aF[f] = *(const bf16x8*)(Qs + (wr * 64 + f * 16 + cn) * 64 + kk +
                                         (lane >> 4) * 8);
                bF[f] = *(const bf16x8*)(PTs + (wc * 64 + f * 16 + cn) * 72 + kk +
                                         (lane >> 4) * 8);
            }
#pragma unroll
            for (int fm = 0; fm < 4; ++fm)
#pragma unroll
                for (int fn = 0; fn < 4; ++fn)
                    acc[fm][fn] = __builtin_amdgcn_mfma_f32_16x16x32_bf16(
                        aF[fm], bF[fn], acc[fm][fn], 0, 0, 0);
        }
        __syncthreads();
    }

    float* ob = out + (size_t)b * LDIM * DOUT;
#pragma unroll
    for (int fm = 0; fm < 4; ++fm)
#pragma unroll
        for (int fn = 0; fn < 4; ++fn)
#pragma unroll
            for (int r = 0; r < 4; ++r) {
                int m = l0 + wr * 64 + fm * 16 + cr4 + r;
                int n = o0 + wc * 64 + fn * 16 + cn;
                ob[(size_t)m * DOUT + n] = acc[fm][fn][r];
            }
}

extern "C" void kernel_launch(void* const* d_in, const int* in_sizes, int n_in,
                              void* d_out, int out_size, void* d_ws, size_t ws_size,
                              hipStream_t stream) {
    const float* x  = (const float*)d_in[0];
    const float* Wq = (const float*)d_in[1];
    const float* Wk = (const float*)d_in[2];
    const float* Wv = (const float*)d_in[3];
    const float* Wo = (const float*)d_in[4];

    k_fused<<<dim3(NBLKF), 256, 0, stream>>>(x, Wq, Wk, Wv, Wo, (char*)d_ws);
    k_out<<<dim3(32, 4, BDIM), 256, 0, stream>>>((const char*)d_ws,
                                                 (float*)d_out);
}

// Round 8
// 147.119 us; speedup vs baseline: 1.1562x; 1.1562x over previous
//
#include <hip/hip_runtime.h>
#include <cstdint>

// out[b] = x[b] @ C[b],  C[b] = sum_h Wq[h] M[b,h] Wo[h],  M = Wk^T (x^T x) Wv
// R18: 3 clean launches + XCD-grouped scheduling for L2 reuse.
// R17 post-mortem: xtx re-reads the same 1MB xT slice 12x across all XCDs
// (~96MB logical, no L2 reuse) -- the invariant ~40-70us chunk in R15-R17.
// Fix: bid%8 = (b,ch) group -> each group's 32 blocks land on ONE XCD,
// slice goes L2-resident; same for Q' (4 nt-tiles per (b,lt) grouped).
// G: bf16 per-chunk partials, agent-scope stores, no atomics/zero-init
// (R17-proven); monotonic epoch gate (replay-safe, R17-proven) releases
// last 128 xtx finishers to run mid (T2=Wk^T G, Mp bf16 partials, plain
// stores; k_out sums them across the launch boundary).  k_prep/k_out:
// R16's passing versions, plain write-back stores.

#define BDIM 2
#define LDIM 4096
#define DIN 512
#define HDIM 8
#define DK 64
#define DV 64
#define DOUT 512
#define NXTX 256
#define NMID 128
#define NCH 4
#define SMEM_MAIN 34816

using bf16_t = __bf16;
typedef __bf16 bf16x8 __attribute__((ext_vector_type(8)));
typedef float floatx4 __attribute__((ext_vector_type(4)));

constexpr size_t OFF_XB  = 0;
constexpr size_t OFF_XT  = OFF_XB  + (size_t)BDIM * LDIM * DIN * 2;
constexpr size_t OFF_WQT = OFF_XT  + (size_t)BDIM * LDIM * DIN * 2;
constexpr size_t OFF_WKT = OFF_WQT + (size_t)HDIM * DK * DIN * 2;
constexpr size_t OFF_WVT = OFF_WKT + (size_t)HDIM * DK * DIN * 2;
constexpr size_t OFF_WOT = OFF_WVT + (size_t)HDIM * DV * DIN * 2;
constexpr size_t OFF_QP  = OFF_WOT + (size_t)HDIM * DOUT * DV * 2;
constexpr size_t OFF_GP  = OFF_QP  + (size_t)BDIM * LDIM * DIN * 2;
constexpr size_t OFF_MP  = OFF_GP  + (size_t)NCH * BDIM * DIN * DIN * 2;

// Monotonic epoch counter: zeroed at module load, NEVER reset.  Each k_main
// launch consumes exactly NXTX increments -> epoch alignment invariant
// across harness iterations AND rocprof replays (R16's 20ms ghost dispatch
// was the resettable counter; R17's monotonic version showed none).
__device__ unsigned g_ctr;

__device__ __forceinline__ unsigned short f2bf(float f) {
    unsigned int u = __builtin_bit_cast(unsigned int, f);
    u += 0x7FFFu + ((u >> 16) & 1u);
    return (unsigned short)(u >> 16);
}

__device__ __forceinline__ float bf2f(unsigned short u) {
    unsigned int v = ((unsigned int)u) << 16;
    return __builtin_bit_cast(float, v);
}

__device__ __forceinline__ void gld_lds16(const void* g, void* l) {
    __builtin_amdgcn_global_load_lds(
        (const __attribute__((address_space(1))) void*)g,
        (__attribute__((address_space(3))) void*)l, 16, 0, 0);
}

// agent-scope relaxed store: write-through to the coherent point (for the
// within-kernel Gp crossing only; everything else uses plain stores).
__device__ __forceinline__ void st_agent32(unsigned short* p, unsigned v) {
    __hip_atomic_store((unsigned*)p, v, __ATOMIC_RELAXED,
                       __HIP_MEMORY_SCOPE_AGENT);
}

// ---------------- TN MFMA GEMM tile (bf16 plain-store epilogue) -----------
template <int BM, int BN, int BK>
__device__ __forceinline__ void gemm_tn(char* smem, const bf16_t* A,
                                        const bf16_t* B, unsigned short* Cp,
                                        int K, int lda, int ldb, int ldc,
                                        int tm, int tn) {
    constexpr int WM = BM / 2, WN = BN / 2;
    constexpr int FM = WM / 16, FN = WN / 16;
    constexpr int CPR = BK / 8;
    bf16_t* As = (bf16_t*)smem;
    bf16_t* Bs = As + BM * BK;
    const int tid = threadIdx.x;
    const int lane = tid & 63;
    const int wr = (tid >> 7) & 1;
    const int wc = (tid >> 6) & 1;

    A += (size_t)tm * lda;
    B += (size_t)tn * ldb;

    floatx4 acc[FM][FN] = {};

    for (int k0 = 0; k0 < K; k0 += BK) {
#pragma unroll
        for (int i = 0; i < (BM * CPR) / 256; ++i) {
            int c = i * 256 + tid;
            int m = c / CPR, kc = c % CPR;
            gld_lds16(A + (size_t)m * lda + k0 + kc * 8, As + c * 8);
        }
#pragma unroll
        for (int i = 0; i < (BN * CPR) / 256; ++i) {
            int c = i * 256 + tid;
            int m = c / CPR, kc = c % CPR;
            gld_lds16(B + (size_t)m * ldb + k0 + kc * 8, Bs + c * 8);
        }
        __syncthreads();

#pragma unroll
        for (int kk = 0; kk < BK; kk += 32) {
            bf16x8 aF[FM], bF[FN];
#pragma unroll
            for (int fm = 0; fm < FM; ++fm)
                aF[fm] = *(const bf16x8*)(As + (wr * WM + fm * 16 + (lane & 15)) * BK +
                                          kk + (lane >> 4) * 8);
#pragma unroll
            for (int fn = 0; fn < FN; ++fn)
                bF[fn] = *(const bf16x8*)(Bs + (wc * WN + fn * 16 + (lane & 15)) * BK +
                                          kk + (lane >> 4) * 8);
#pragma unroll
            for (int fm = 0; fm < FM; ++fm)
#pragma unroll
                for (int fn = 0; fn < FN; ++fn)
                    acc[fm][fn] = __builtin_amdgcn_mfma_f32_16x16x32_bf16(
                        aF[fm], bF[fn], acc[fm][fn], 0, 0, 0);
        }
        __syncthreads();
    }

    const int cr4 = (lane >> 4) * 4;
    const int cn = lane & 15;
#pragma unroll
    for (int fm = 0; fm < FM; ++fm)
#pragma unroll
        for (int fn = 0; fn < FN; ++fn)
#pragma unroll
            for (int r = 0; r < 4; ++r) {
                int m = tm + wr * WM + fm * 16 + cr4 + r;
                int n = tn + wc * WN + fn * 16 + cn;
                Cp[(size_t)m * ldc + n] = f2bf(acc[fm][fn][r]);
            }
}

// ---------------- K1: prep (plain write-back stores, R16's) ---------------
// bids: [0,1024) x->xb16+xT | [1024,1280) W transposes
__global__ __launch_bounds__(256) void k_prep(
    const float* __restrict__ x, const float* __restrict__ Wq,
    const float* __restrict__ Wk, const float* __restrict__ Wv,
    const float* __restrict__ Wo, char* __restrict__ ws) {
    __shared__ unsigned short T[64][65];
    unsigned short* xb  = (unsigned short*)(ws + OFF_XB);
    unsigned short* xT  = (unsigned short*)(ws + OFF_XT);
    unsigned short* WqT = (unsigned short*)(ws + OFF_WQT);
    unsigned short* WkT = (unsigned short*)(ws + OFF_WKT);
    unsigned short* WvT = (unsigned short*)(ws + OFF_WVT);
    unsigned short* WoT = (unsigned short*)(ws + OFF_WOT);

    const int tid = threadIdx.x;
    const int tr = tid >> 4, tc4 = (tid & 15) * 4;
    const int j = blockIdx.x;

    if (j < 1024) {  // x 64x64 tile -> xb (row-major) + xT (transposed)
        const int b = j >> 9, q = j & 511, lt = q >> 3, it = q & 7;
        const float* src = x + (size_t)b * LDIM * DIN + (size_t)lt * 64 * DIN +
                           it * 64;
        unsigned short* d0 = xb + (size_t)b * LDIM * DIN +
                             (size_t)lt * 64 * DIN + it * 64;
        unsigned short* d1 = xT + (size_t)b * DIN * LDIM +
                             (size_t)it * 64 * LDIM + lt * 64;
#pragma unroll
        for (int p = 0; p < 4; ++p) {
            int r = p * 16 + tr;
            float4 v = *(const float4*)(src + (size_t)r * DIN + tc4);
            ushort4 u = make_ushort4(f2bf(v.x), f2bf(v.y), f2bf(v.z), f2bf(v.w));
            *(ushort4*)(d0 + (size_t)r * DIN + tc4) = u;
            T[r][tc4 + 0] = u.x; T[r][tc4 + 1] = u.y;
            T[r][tc4 + 2] = u.z; T[r][tc4 + 3] = u.w;
        }
        __syncthreads();
#pragma unroll
        for (int p = 0; p < 4; ++p) {
            int c = p * 16 + tr;
            ushort4 u = make_ushort4(T[tc4 + 0][c], T[tc4 + 1][c], T[tc4 + 2][c],
                                     T[tc4 + 3][c]);
            *(ushort4*)(d1 + (size_t)c * LDIM + tc4) = u;
        }
        return;
    }
    {  // weight transposes -> bf16, k-contiguous layouts
        const int q = j - 1024;
        const int t = q & 7, h = (q >> 3) & 7, typ = q >> 6;
        const float* src;
        unsigned short* dst;
        int rows, cols, r0, c0;
        if (typ == 0) { src = Wq + (size_t)h * DIN * DK; dst = WqT + (size_t)h * DK * DIN;
                        rows = DIN; cols = DK; r0 = t * 64; c0 = 0; }
        else if (typ == 1) { src = Wk + (size_t)h * DIN * DK; dst = WkT + (size_t)h * DK * DIN;
                        rows = DIN; cols = DK; r0 = t * 64; c0 = 0; }
        else if (typ == 2) { src = Wv + (size_t)h * DIN * DV; dst = WvT + (size_t)h * DV * DIN;
                        rows = DIN; cols = DV; r0 = t * 64; c0 = 0; }
        else { src = Wo + (size_t)h * DV * DOUT; dst = WoT + (size_t)h * DOUT * DV;
                        rows = DV; cols = DOUT; r0 = 0; c0 = t * 64; }
#pragma unroll
        for (int p = 0; p < 4; ++p) {
            int r = p * 16 + tr;
            float4 v = *(const float4*)(src + (size_t)(r0 + r) * cols + c0 + tc4);
            T[r][tc4 + 0] = f2bf(v.x); T[r][tc4 + 1] = f2bf(v.y);
            T[r][tc4 + 2] = f2bf(v.z); T[r][tc4 + 3] = f2bf(v.w);
        }
        __syncthreads();
#pragma unroll
        for (int p = 0; p < 4; ++p) {
            int c = p * 16 + tr;
            ushort4 u = make_ushort4(T[tc4 + 0][c], T[tc4 + 1][c], T[tc4 + 2][c],
                                     T[tc4 + 3][c]);
            *(ushort4*)(dst + (size_t)(c0 + c) * rows + r0 + tc4) = u;
        }
    }
}

// ---------------- xtx job: bf16 G chunk-partial, agent stores -------------
// 128x64 tile of Gram(xT chunk); partial is symmetric -> transposed packing
// (m-pairs in-lane at [n][m]) stores the same matrix row-major.
__device__ void xtx_job(int b, int ch, int i0, int j0, char* smem,
                        const bf16_t* xT, unsigned short* GpB) {
    const int tid = threadIdx.x, lane = tid & 63;
    const int wr = (tid >> 7) & 1, wc = (tid >> 6) & 1;
    const int cr4 = (lane >> 4) * 4, cn = lane & 15;
    bf16_t* As = (bf16_t*)smem;   // 128x64
    bf16_t* Bs = As + 128 * 64;   // 64x64
    const bf16_t* Ag = xT + (size_t)b * DIN * LDIM + ch * 1024 +
                       (size_t)i0 * LDIM;
    const bf16_t* Bg = xT + (size_t)b * DIN * LDIM + ch * 1024 +
                       (size_t)j0 * LDIM;

    floatx4 acc[4][2] = {};
    for (int k0 = 0; k0 < 1024; k0 += 64) {
#pragma unroll
        for (int i = 0; i < 4; ++i) {
            int c = i * 256 + tid, m = c >> 3, kc = c & 7;
            gld_lds16(Ag + (size_t)m * LDIM + k0 + kc * 8, As + c * 8);
        }
#pragma unroll
        for (int i = 0; i < 2; ++i) {
            int c = i * 256 + tid, m = c >> 3, kc = c & 7;
            gld_lds16(Bg + (size_t)m * LDIM + k0 + kc * 8, Bs + c * 8);
        }
        __syncthreads();
#pragma unroll
        for (int kk = 0; kk < 64; kk += 32) {
            bf16x8 aF[4], bF[2];
#pragma unroll
            for (int fm = 0; fm < 4; ++fm)
                aF[fm] = *(const bf16x8*)(As + (wr * 64 + fm * 16 + cn) * 64 +
                                          kk + (lane >> 4) * 8);
#pragma unroll
            for (int fn = 0; fn < 2; ++fn)
                bF[fn] = *(const bf16x8*)(Bs + (wc * 32 + fn * 16 + cn) * 64 +
                                          kk + (lane >> 4) * 8);
#pragma unroll
            for (int fm = 0; fm < 4; ++fm)
#pragma unroll
                for (int fn = 0; fn < 2; ++fn)
                    acc[fm][fn] = __builtin_amdgcn_mfma_f32_16x16x32_bf16(
                        aF[fm], bF[fn], acc[fm][fn], 0, 0, 0);
        }
        __syncthreads();
    }

    unsigned short* Gt = GpB + (size_t)(ch * 2 + b) * DIN * DIN;
#pragma unroll
    for (int fm = 0; fm < 4; ++fm)
#pragma unroll
        for (int fn = 0; fn < 2; ++fn) {
            int m = i0 + wr * 64 + fm * 16 + cr4;
            int n = j0 + wc * 32 + fn * 16 + cn;
            unsigned a01 = (unsigned)f2bf(acc[fm][fn][0]) |
                           ((unsigned)f2bf(acc[fm][fn][1]) << 16);
            unsigned a23 = (unsigned)f2bf(acc[fm][fn][2]) |
                           ((unsigned)f2bf(acc[fm][fn][3]) << 16);
            st_agent32(Gt + (size_t)n * DIN + m, a01);
            st_agent32(Gt + (size_t)n * DIN + m + 2, a23);
        }
}

// ---------------- mid job: T2 = Wk^T G (sum 4 partials), Mp bf16 ----------
__device__ void mid_job(int id, char* smem, const bf16_t* WkT,
                        const bf16_t* WvT, const unsigned short* GpB,
                        unsigned short* Mp) {
    const int tid = threadIdx.x, lane = tid & 63;
    const int wr = (tid >> 7) & 1, wc = (tid >> 6) & 1;
    const int cr4 = (lane >> 4) * 4, cn = lane & 15;
    const int h = id & 7, b = (id >> 3) & 1, jt = id >> 4;  // jt 0..7
    const int j0 = jt * 64;
    bf16_t* As  = (bf16_t*)smem;                 // 64x64
    bf16_t* Bs  = (bf16_t*)(smem + 8192);        // 64x64
    bf16_t* T2s = (bf16_t*)(smem + 16384);       // [64][72]
    bf16_t* Vs  = (bf16_t*)(smem + 25600);       // 64x64
    const bf16_t* Ah = WkT + (size_t)h * DK * DIN;
    const bf16_t* Vh = WvT + (size_t)h * DV * DIN;

    floatx4 accT[2][2] = {};
    for (int k0 = 0; k0 < DIN; k0 += 64) {
#pragma unroll
        for (int i = 0; i < 2; ++i) {
            int c = i * 256 + tid, m = c >> 3, kc = c & 7;
            gld_lds16(Ah + (size_t)m * DIN + k0 + kc * 8, As + c * 8);
        }
#pragma unroll
        for (int i = 0; i < 2; ++i) {
            int c = i * 256 + tid, n = c >> 3, kc = c & 7;
            const unsigned short* g = GpB + (size_t)b * DIN * DIN +
                                      (size_t)(j0 + n) * DIN + k0 + kc * 8;
            float s[8] = {0.f, 0.f, 0.f, 0.f, 0.f, 0.f, 0.f, 0.f};
#pragma unroll
            for (int ch = 0; ch < NCH; ++ch) {
                uint4 u = *(const uint4*)(g + (size_t)ch * 2 * DIN * DIN);
                const unsigned short* e = (const unsigned short*)&u;
#pragma unroll
                for (int q = 0; q < 8; ++q) s[q] += bf2f(e[q]);
            }
            unsigned short o[8];
#pragma unroll
            for (int q = 0; q < 8; ++q) o[q] = f2bf(s[q]);
            *(uint4*)((unsigned short*)Bs + (size_t)c * 8) = *(const uint4*)o;
        }
        __syncthreads();
#pragma unroll
        for (int kk = 0; kk < 64; kk += 32) {
            bf16x8 aF[2], bF[2];
#pragma unroll
            for (int f = 0; f < 2; ++f) {
                aF[f] = *(const bf16x8*)(As + (wr * 32 + f * 16 + cn) * 64 + kk +
                                         (lane >> 4) * 8);
                bF[f] = *(const bf16x8*)(Bs + (wc * 32 + f * 16 + cn) * 64 + kk +
                                         (lane >> 4) * 8);
            }
#pragma unroll
            for (int fm = 0; fm < 2; ++fm)
#pragma unroll
                for (int fn = 0; fn < 2; ++fn)
                    accT[fm][fn] = __builtin_amdgcn_mfma_f32_16x16x32_bf16(
                        aF[fm], bF[fn], accT[fm][fn], 0, 0, 0);
        }
        __syncthreads();
    }
    // accT -> T2s [dk][j] (pad 72), stage Wv j-slice
#pragma unroll
    for (int fm = 0; fm < 2; ++fm)
#pragma unroll
        for (int fn = 0; fn < 2; ++fn)
#pragma unroll
            for (int r = 0; r < 4; ++r)
                ((unsigned short*)T2s)[(wr * 32 + fm * 16 + cr4 + r) * 72 +
                                       wc * 32 + fn * 16 + cn] =
                    f2bf(accT[fm][fn][r]);
#pragma unroll
    for (int i = 0; i < 2; ++i) {
        int c = i * 256 + tid, v = c >> 3, kc = c & 7;
        gld_lds16(Vh + (size_t)v * DIN + j0 + kc * 8, Vs + c * 8);
    }
    __syncthreads();

    floatx4 accM[2][2] = {};
#pragma unroll
    for (int kk = 0; kk < 64; kk += 32) {
        bf16x8 aF[2], bF[2];
#pragma unroll
        for (int f = 0; f < 2; ++f) {
            aF[f] = *(const bf16x8*)(T2s + (wr * 32 + f * 16 + cn) * 72 + kk +
                                     (lane >> 4) * 8);
            bF[f] = *(const bf16x8*)(Vs + (wc * 32 + f * 16 + cn) * 64 + kk +
                                     (lane >> 4) * 8);
        }
#pragma unroll
        for (int fm = 0; fm < 2; ++fm)
#pragma unroll
            for (int fn = 0; fn < 2; ++fn)
                accM[fm][fn] = __builtin_amdgcn_mfma_f32_16x16x32_bf16(
                    aF[fm], bF[fn], accM[fm][fn], 0, 0, 0);
    }
    unsigned short* MpD = Mp + ((size_t)((jt * BDIM + b) * HDIM + h)) * (DK * DV);
#pragma unroll
    for (int fm = 0; fm < 2; ++fm)
#pragma unroll
        for (int fn = 0; fn < 2; ++fn)
#pragma unroll
            for (int r = 0; r < 4; ++r)
                MpD[(wr * 32 + fm * 16 + cr4 + r) * 64 + wc * 32 + fn * 16 + cn] =
                    f2bf(accM[fm][fn][r]);
}

// ---------------- K2: main (XCD-grouped xtx + Q' + gated mid) -------------
__global__ __launch_bounds__(256) void k_main(char* __restrict__ ws) {
    __shared__ __align__(16) char smem[SMEM_MAIN];
    __shared__ unsigned s_rank;
    const bf16_t* xb  = (const bf16_t*)(ws + OFF_XB);
    const bf16_t* xT  = (const bf16_t*)(ws + OFF_XT);
    const bf16_t* WqT = (const bf16_t*)(ws + OFF_WQT);
    const bf16_t* WkT = (const bf16_t*)(ws + OFF_WKT);
    const bf16_t* WvT = (const bf16_t*)(ws + OFF_WVT);
    unsigned short* Qp  = (unsigned short*)(ws + OFF_QP);
    unsigned short* GpB = (unsigned short*)(ws + OFF_GP);
    unsigned short* Mp  = (unsigned short*)(ws + OFF_MP);

    const int bid = blockIdx.x;
    const int tid = threadIdx.x;

    if (bid < NXTX) {
        // XCD group g = bid%8 = (b,ch); 32 tile-jobs per group share a 1MB
        // xT slice -> L2-resident on that XCD.
        const int g = bid & 7, t = bid >> 3;
        const int b = g & 1, ch = g >> 1;
        const int i0 = (t >> 3) * 128, j0 = (t & 7) * 64;
        xtx_job(b, ch, i0, j0, smem, xT, GpB);
        // epoch gate (monotonic, replay-safe); last NMID finishers run mid
        __syncthreads();
        if (tid == 0) {
            unsigned old = __hip_atomic_fetch_add(&g_ctr, 1u, __ATOMIC_RELAXED,
                                                  __HIP_MEMORY_SCOPE_AGENT);
            s_rank = old & (NXTX - 1);
            if (s_rank >= NXTX - NMID) {
                unsigned tgt = (old | (NXTX - 1)) + 1;
                while ((int)(__hip_atomic_load(&g_ctr, __ATOMIC_RELAXED,
                                               __HIP_MEMORY_SCOPE_AGENT) -
                             tgt) < 0)
                    __builtin_amdgcn_s_sleep(8);
            }
        }
        __syncthreads();
        if (s_rank >= NXTX - NMID)
            mid_job((int)s_rank - (NXTX - NMID), smem, WkT, WvT, GpB, Mp);
    } else {
        // Q' 128x128 tiles; group 4 nt-jobs per (b,lt) on one XCD
        // (q%8 = gid%8): shared 128KB xb panel + 512KB WqT -> L2-resident.
        const int q = bid - NXTX;
        const int gid = q & 63, nt = q >> 6;
        const int b = gid >> 5, lt = gid & 31;
        gemm_tn<128, 128, 64>(smem, xb + (size_t)b * LDIM * DIN, WqT,
                              Qp + (size_t)b * LDIM * (HDIM * DK), DIN, DIN,
                              DIN, HDIM * DK, lt * 128, nt * 128);
    }
}

// ---------------- K3: out' (unchanged, passing since R15) -----------------
__global__ __launch_bounds__(256) void k_out(const char* __restrict__ ws,
                                             float* __restrict__ out) {
    __shared__ __align__(16) bf16_t Qs[128 * 64];
    __shared__ __align__(16) bf16_t Ws[128 * 64];
    __shared__ __align__(16) bf16_t Ms[64 * 72];
    __shared__ __align__(16) bf16_t PTs[128 * 72];
    const bf16_t* WoT = (const bf16_t*)(ws + OFF_WOT);
    const bf16_t* Qp  = (const bf16_t*)(ws + OFF_QP);
    const unsigned short* Mp = (const unsigned short*)(ws + OFF_MP);

    const int lt = blockIdx.x, nt = blockIdx.y, b = blockIdx.z;
    const int l0 = lt * 128, o0 = nt * 128;
    const int tid = threadIdx.x, lane = tid & 63;
    const int wr = (tid >> 7) & 1, wc = (tid >> 6) & 1;
    const int cr4 = (lane >> 4) * 4, cn = lane & 15;

    floatx4 acc[4][4] = {};

    for (int h = 0; h < HDIM; ++h) {
        // stage Ms: sum 8 bf16 jt-partials -> bf16 [dk][v] (pad 72)
        {
            const int dk = tid >> 2, v0 = (tid & 3) * 16;
            float s[16] = {0.f, 0.f, 0.f, 0.f, 0.f, 0.f, 0.f, 0.f,
                           0.f, 0.f, 0.f, 0.f, 0.f, 0.f, 0.f, 0.f};
#pragma unroll
            for (int p = 0; p < 8; ++p) {
                const unsigned short* mp =
                    Mp + ((size_t)((p * BDIM + b) * HDIM + h)) * (DK * DV) +
                    dk * 64 + v0;
                uint4 u0 = *(const uint4*)mp;
                uint4 u1 = *(const uint4*)(mp + 8);
                const unsigned short* e0 = (const unsigned short*)&u0;
                const unsigned short* e1 = (const unsigned short*)&u1;
#pragma unroll
                for (int q = 0; q < 8; ++q) {
                    s[q] += bf2f(e0[q]);
                    s[8 + q] += bf2f(e1[q]);
                }
            }
            unsigned short o[16];
#pragma unroll
            for (int q = 0; q < 16; ++q) o[q] = f2bf(s[q]);
            unsigned short* d = (unsigned short*)Ms + dk * 72 + v0;
            *(uint4*)d = *(const uint4*)o;
            *(uint4*)(d + 8) = *(const uint4*)(o + 8);
        }
#pragma unroll
        for (int i = 0; i < 4; ++i) {
            int c = i * 256 + tid, m = c >> 3, kc = c & 7;
            gld_lds16(WoT + ((size_t)h * DOUT + o0 + m) * DV + kc * 8,
                      Ws + c * 8);
            gld_lds16(Qp + (size_t)b * LDIM * 512 + (size_t)(l0 + m) * 512 +
                          h * 64 + kc * 8,
                      Qs + c * 8);
        }
        __syncthreads();

        floatx4 accP[2][4] = {};
#pragma unroll
        for (int kk = 0; kk < 64; kk += 32) {
            bf16x8 aF[2], bF[4];
#pragma unroll
            for (int f = 0; f < 2; ++f)
                aF[f] = *(const bf16x8*)(Ms + (wr * 32 + f * 16 + cn) * 72 + kk +
                                         (lane >> 4) * 8);
#pragma unroll
            for (int f = 0; f < 4; ++f)
                bF[f] = *(const bf16x8*)(Ws + (wc * 64 + f * 16 + cn) * 64 + kk +
                                         (lane >> 4) * 8);
#pragma unroll
            for (int fm = 0; fm < 2; ++fm)
#pragma unroll
                for (int fn = 0; fn < 4; ++fn)
                    accP[fm][fn] = __builtin_amdgcn_mfma_f32_16x16x32_bf16(
                        aF[fm], bF[fn], accP[fm][fn], 0, 0, 0);
        }
#pragma unroll
        for (int fm = 0; fm < 2; ++fm)
#pragma unroll
            for (int fn = 0; fn < 4; ++fn)
#pragma unroll
                for (int r = 0; r < 4; ++r)
                    ((unsigned short*)PTs)[(wc * 64 + fn * 16 + cn) * 72 +
                                           wr * 32 + fm * 16 + cr4 + r] =
                        f2bf(accP[fm][fn][r]);
        __syncthreads();

#pragma unroll
        for (int kk = 0; kk < 64; kk += 32) {
            bf16x8 aF[4], bF[4];
#pragma unroll
            for (int f = 0; f < 4; ++f) {
                aF[f] = *(const bf16x8*)(Qs + (wr * 64 + f * 16 + cn) * 64 + kk +
                                         (lane >> 4) * 8);
                bF[f] = *(const bf16x8*)(PTs + (wc * 64 + f * 16 + cn) * 72 + kk +
                                         (lane >> 4) * 8);
            }
#pragma unroll
            for (int fm = 0; fm < 4; ++fm)
#pragma unroll
                for (int fn = 0; fn < 4; ++fn)
                    acc[fm][fn] = __builtin_amdgcn_mfma_f32_16x16x32_bf16(
                        aF[fm], bF[fn], acc[fm][fn], 0, 0, 0);
        }
        __syncthreads();
    }

    float* ob = out + (size_t)b * LDIM * DOUT;
#pragma unroll
    for (int fm = 0; fm < 4; ++fm)
#pragma unroll
        for (int fn = 0; fn < 4; ++fn)
#pragma unroll
            for (int r = 0; r < 4; ++r) {
                int m = l0 + wr * 64 + fm * 16 + cr4 + r;
                int n = o0 + wc * 64 + fn * 16 + cn;
                ob[(size_t)m * DOUT + n] = acc[fm][fn][r];
            }
}

extern "C" void kernel_launch(void* const* d_in, const int* in_sizes, int n_in,
                              void* d_out, int out_size, void* d_ws, size_t ws_size,
                              hipStream_t stream) {
    const float* x  = (const float*)d_in[0];
    const float* Wq = (const float*)d_in[1];
    const float* Wk = (const float*)d_in[2];
    const float* Wv = (const float*)d_in[3];
    const float* Wo = (const float*)d_in[4];

    k_prep<<<dim3(1280), 256, 0, stream>>>(x, Wq, Wk, Wv, Wo, (char*)d_ws);
    k_main<<<dim3(512), 256, 0, stream>>>((char*)d_ws);
    k_out<<<dim3(32, 4, BDIM), 256, 0, stream>>>((const char*)d_ws,
                                                 (float*)d_out);
}